// Round 4
// baseline (240.487 us; speedup 1.0000x reference)
//
#include <hip/hip_runtime.h>
#include <cstdint>
#include <cstddef>

#define DIN 512
#define DH  96
#define DOUT 40
#define BM2 64

typedef __attribute__((ext_vector_type(8))) short s8v;
typedef __attribute__((ext_vector_type(4))) float f4v;

__device__ __forceinline__ ushort f2bf(float f) {
    uint u = __float_as_uint(f);
    u += 0x7fffu + ((u >> 16) & 1u);   // RNE
    return (ushort)(u >> 16);
}

// ---------- zero fill (replaces hipMemsetAsync: rocclr fill was 57us!) ----------
__global__ __launch_bounds__(256) void k_zero(int* __restrict__ p, int n) {
    int i = blockIdx.x * 256 + threadIdx.x;
    if (i < n) p[i] = 0;
}

// ---------- W1 -> bf16 transposed [96][512] ----------
__global__ __launch_bounds__(256) void k_w1t(const float* __restrict__ W1, ushort* __restrict__ W1T) {
    int tg = blockIdx.x * 256 + threadIdx.x;   // 0 .. 49151
    int k = tg / DH, n = tg % DH;
    W1T[(size_t)n * DIN + k] = f2bf(W1[tg]);
}

// ---------- CSR build ----------
__global__ __launch_bounds__(256) void k_hist(const int* __restrict__ dst, int* __restrict__ cnt, int E) {
    int e = blockIdx.x * 256 + threadIdx.x;
    if (e < E) atomicAdd(&cnt[dst[e]], 1);
}

__global__ __launch_bounds__(256) void k_blocksum(const int* __restrict__ cnt, int* __restrict__ bsum, int N) {
    int i = blockIdx.x * 256 + threadIdx.x;
    int c = (i < N) ? cnt[i] : 0;
    #pragma unroll
    for (int off = 32; off >= 1; off >>= 1) c += __shfl_down(c, off, 64);
    __shared__ int wsum[4];
    if ((threadIdx.x & 63) == 0) wsum[threadIdx.x >> 6] = c;
    __syncthreads();
    if (threadIdx.x == 0) bsum[blockIdx.x] = wsum[0] + wsum[1] + wsum[2] + wsum[3];
}

__global__ __launch_bounds__(256) void k_scan_small(const int* __restrict__ bsum, int* __restrict__ boff, int SB) {
    __shared__ int p[256];
    int tid = threadIdx.x;
    int v = (tid < SB) ? bsum[tid] : 0;
    p[tid] = v;
    __syncthreads();
    #pragma unroll
    for (int off = 1; off < 256; off <<= 1) {
        int t = (tid >= off) ? p[tid - off] : 0;
        __syncthreads();
        p[tid] += t;
        __syncthreads();
    }
    if (tid < SB) boff[tid] = p[tid] - v;   // exclusive
}

__global__ __launch_bounds__(256) void k_rowptr(
    const int* __restrict__ cnt, const int* __restrict__ boff,
    int* __restrict__ row_ptr, int* __restrict__ cursor,
    float* __restrict__ dinv, int N)
{
    __shared__ int p[256];
    int tid = threadIdx.x;
    int i = blockIdx.x * 256 + tid;
    int c = (i < N) ? cnt[i] : 0;
    p[tid] = c;
    __syncthreads();
    #pragma unroll
    for (int off = 1; off < 256; off <<= 1) {
        int t = (tid >= off) ? p[tid - off] : 0;
        __syncthreads();
        p[tid] += t;
        __syncthreads();
    }
    int excl = p[tid] - c;
    if (i < N) {
        int base = boff[blockIdx.x] + excl;
        row_ptr[i] = base;
        cursor[i]  = base;                       // fill cursor here: no memset needed
        dinv[i] = rsqrtf(1.0f + (float)c);
        if (i == N - 1) row_ptr[N] = base + c;
    }
}

__global__ __launch_bounds__(256) void k_fill(
    const int* __restrict__ src, const int* __restrict__ dst,
    int* __restrict__ cursor, int* __restrict__ adj, int E)
{
    int e = blockIdx.x * 256 + threadIdx.x;
    if (e >= E) return;
    int pos = atomicAdd(&cursor[dst[e]], 1);
    adj[pos] = src[e];
}

// ---------- GEMM1 (MFMA bf16): hs1 = (x @ W1) * dinv ----------
// block tile 128 rows x 96 cols, BK=64, 4 waves (2x2), wave tile 64x48
#define G1_ASZ 8192   // 128*64 halfwords
#define G1_BSZ 6144   // 96*64 halfwords
__global__ __launch_bounds__(256) void k_gemm1(
    const float* __restrict__ x, const ushort* __restrict__ W1T,
    const float* __restrict__ dinv, float* __restrict__ hs1, int N)
{
    __shared__ ushort lds[2 * G1_ASZ + 2 * G1_BSZ];   // 56 KiB
    const int tid = threadIdx.x;
    const int row0 = blockIdx.x * 128;
    const int lane = tid & 63;
    const int w = tid >> 6;
    const int rb = (w >> 1) * 64;
    const int cb = (w & 1) * 48;
    const int lm = lane & 15;
    const int lq = lane >> 4;

    int aof[4][2], bof[3][2];
    #pragma unroll
    for (int i = 0; i < 4; ++i)
        #pragma unroll
        for (int ks = 0; ks < 2; ++ks) {
            int r = rb + i * 16 + lm;
            int c = ks * 32 + lq * 8;
            aof[i][ks] = r * 64 + (c ^ ((r & 7) << 3));
        }
    #pragma unroll
    for (int j = 0; j < 3; ++j)
        #pragma unroll
        for (int ks = 0; ks < 2; ++ks) {
            int n = cb + j * 16 + lm;
            int c = ks * 32 + lq * 8;
            bof[j][ks] = 2 * G1_ASZ + n * 64 + (c ^ ((n & 7) << 3));
        }

    f4v acc[4][3];
    #pragma unroll
    for (int i = 0; i < 4; ++i)
        #pragma unroll
        for (int j = 0; j < 3; ++j) acc[i][j] = (f4v)0.f;

    const int sr = tid >> 1;
    const int scb = (tid & 1) * 32;

    auto stage = [&](int kt, int buf) {
        int k0 = kt * 64;
        int gr = row0 + sr;
        ushort* A = lds + buf * G1_ASZ;
        #pragma unroll
        for (int s = 0; s < 4; ++s) {
            int c = scb + s * 8;
            float4 v0 = make_float4(0.f, 0.f, 0.f, 0.f), v1 = v0;
            if (gr < N) {
                const float* p = &x[(size_t)gr * DIN + k0 + c];
                v0 = *(const float4*)p;
                v1 = *(const float4*)(p + 4);
            }
            uint4 wv;
            wv.x = (uint)f2bf(v0.x) | ((uint)f2bf(v0.y) << 16);
            wv.y = (uint)f2bf(v0.z) | ((uint)f2bf(v0.w) << 16);
            wv.z = (uint)f2bf(v1.x) | ((uint)f2bf(v1.y) << 16);
            wv.w = (uint)f2bf(v1.z) | ((uint)f2bf(v1.w) << 16);
            *(uint4*)&A[sr * 64 + (c ^ ((sr & 7) << 3))] = wv;
        }
        ushort* B = lds + 2 * G1_ASZ + buf * G1_BSZ;
        #pragma unroll
        for (int it = 0; it < 3; ++it) {
            int ss = tid + it * 256;
            int n = ss >> 3, c = (ss & 7) * 8;
            uint4 wv = *(const uint4*)&W1T[(size_t)n * DIN + k0 + c];
            *(uint4*)&B[n * 64 + (c ^ ((n & 7) << 3))] = wv;
        }
    };

    stage(0, 0);
    for (int kt = 0; kt < 8; ++kt) {
        __syncthreads();
        if (kt < 7) stage(kt + 1, (kt + 1) & 1);
        const int ab = (kt & 1) * G1_ASZ;
        const int bb = (kt & 1) * G1_BSZ;
        #pragma unroll
        for (int ks = 0; ks < 2; ++ks) {
            s8v b0 = *(s8v*)&lds[bof[0][ks] + bb];
            s8v b1 = *(s8v*)&lds[bof[1][ks] + bb];
            s8v b2 = *(s8v*)&lds[bof[2][ks] + bb];
            #pragma unroll
            for (int i = 0; i < 4; ++i) {
                s8v a = *(s8v*)&lds[aof[i][ks] + ab];
                acc[i][0] = __builtin_amdgcn_mfma_f32_16x16x32_bf16(a, b0, acc[i][0], 0, 0, 0);
                acc[i][1] = __builtin_amdgcn_mfma_f32_16x16x32_bf16(a, b1, acc[i][1], 0, 0, 0);
                acc[i][2] = __builtin_amdgcn_mfma_f32_16x16x32_bf16(a, b2, acc[i][2], 0, 0, 0);
            }
        }
    }

    #pragma unroll
    for (int i = 0; i < 4; ++i) {
        int gr0 = row0 + rb + i * 16 + lq * 4;
        #pragma unroll
        for (int q = 0; q < 4; ++q) {
            int gr = gr0 + q;
            if (gr < N) {
                float di = dinv[gr];
                #pragma unroll
                for (int j = 0; j < 3; ++j)
                    hs1[(size_t)gr * DH + cb + j * 16 + lm] = acc[i][j][q] * di;
            }
        }
    }
}

// ---------- aggregate layer1 (gather) + bias + relu ----------
__global__ __launch_bounds__(256) void k_agg1(
    const int* __restrict__ row_ptr, const int* __restrict__ adj,
    const float* __restrict__ dinv, const float* __restrict__ hs1,
    const float* __restrict__ b1, float* __restrict__ h1, int N)
{
    int t = blockIdx.x * 256 + threadIdx.x;
    int node = t / 24, c4 = t % 24;
    if (node >= N) return;
    int c = c4 * 4;
    float4 acc = *(const float4*)&hs1[(size_t)node * DH + c];  // self-loop
    int e0 = row_ptr[node], e1 = row_ptr[node + 1];
    for (int e = e0; e < e1; ++e) {
        int s = adj[e];
        float4 v = *(const float4*)&hs1[(size_t)s * DH + c];
        acc.x += v.x; acc.y += v.y; acc.z += v.z; acc.w += v.w;
    }
    float di = dinv[node];
    float4 bb = *(const float4*)&b1[c];
    float4 r;
    r.x = fmaxf(fmaf(acc.x, di, bb.x), 0.f);
    r.y = fmaxf(fmaf(acc.y, di, bb.y), 0.f);
    r.z = fmaxf(fmaf(acc.z, di, bb.z), 0.f);
    r.w = fmaxf(fmaf(acc.w, di, bb.w), 0.f);
    *(float4*)&h1[(size_t)node * DH + c] = r;
}

// ---------- GEMM2 (f32): hs2 = (h1 @ W2) * dinv ----------
__global__ __launch_bounds__(256) void k_gemm2(
    const float* __restrict__ h1, const float* __restrict__ W2,
    const float* __restrict__ dinv, float* __restrict__ hs2, int N)
{
    __shared__ float Hs[BM2][DH + 1];
    __shared__ float Ws[DH][DOUT];

    const int tid  = threadIdx.x;
    const int row0 = blockIdx.x * BM2;

    for (int f = tid; f < DH * DOUT / 4; f += 256) {
        int r = f / 10, c4 = (f % 10) << 2;
        *(float4*)&Ws[r][c4] = *(const float4*)&W2[(size_t)r * DOUT + c4];
    }
    for (int f = tid; f < BM2 * DH / 4; f += 256) {
        int r = f / 24, c4 = (f % 24) << 2;
        int gr = row0 + r;
        float4 v = make_float4(0.f, 0.f, 0.f, 0.f);
        if (gr < N) v = *(const float4*)&h1[(size_t)gr * DH + c4];
        Hs[r][c4 + 0] = v.x; Hs[r][c4 + 1] = v.y;
        Hs[r][c4 + 2] = v.z; Hs[r][c4 + 3] = v.w;
    }
    __syncthreads();

    const int tx = tid & 7;
    const int ty = tid >> 3;
    float acc[2][5];
    #pragma unroll
    for (int i = 0; i < 2; ++i)
        #pragma unroll
        for (int j = 0; j < 5; ++j) acc[i][j] = 0.f;

    for (int k = 0; k < DH; ++k) {
        float a0 = Hs[ty * 2 + 0][k];
        float a1 = Hs[ty * 2 + 1][k];
        float b[5];
        #pragma unroll
        for (int j = 0; j < 5; ++j) b[j] = Ws[k][tx * 5 + j];
        #pragma unroll
        for (int j = 0; j < 5; ++j) {
            acc[0][j] = fmaf(a0, b[j], acc[0][j]);
            acc[1][j] = fmaf(a1, b[j], acc[1][j]);
        }
    }

    #pragma unroll
    for (int i = 0; i < 2; ++i) {
        int gr = row0 + ty * 2 + i;
        if (gr < N) {
            float di = dinv[gr];
            #pragma unroll
            for (int j = 0; j < 5; ++j)
                hs2[(size_t)gr * DOUT + tx * 5 + j] = acc[i][j] * di;
        }
    }
}

// ---------- aggregate layer2 (gather) + bias -> logits ----------
__global__ __launch_bounds__(256) void k_agg2(
    const int* __restrict__ row_ptr, const int* __restrict__ adj,
    const float* __restrict__ dinv, const float* __restrict__ hs2,
    const float* __restrict__ b2, float* __restrict__ out, int N)
{
    int t = blockIdx.x * 256 + threadIdx.x;
    int node = t / 10, c4 = t % 10;
    if (node >= N) return;
    int c = c4 * 4;
    float4 acc = *(const float4*)&hs2[(size_t)node * DOUT + c];  // self-loop
    int e0 = row_ptr[node], e1 = row_ptr[node + 1];
    for (int e = e0; e < e1; ++e) {
        int s = adj[e];
        float4 v = *(const float4*)&hs2[(size_t)s * DOUT + c];
        acc.x += v.x; acc.y += v.y; acc.z += v.z; acc.w += v.w;
    }
    float di = dinv[node];
    float4 bb = *(const float4*)&b2[c];
    float4 r;
    r.x = fmaf(acc.x, di, bb.x);
    r.y = fmaf(acc.y, di, bb.y);
    r.z = fmaf(acc.z, di, bb.z);
    r.w = fmaf(acc.w, di, bb.w);
    *(float4*)&out[(size_t)node * DOUT + c] = r;
}

// ---------- log_softmax (wave per row) ----------
__global__ __launch_bounds__(256) void k_softmax(
    const float* __restrict__ logits, float* __restrict__ lsm, int N)
{
    int t = blockIdx.x * 256 + threadIdx.x;
    int row = t >> 6, lane = t & 63;
    if (row >= N) return;
    float v = -1e30f;
    if (lane < DOUT) v = logits[(size_t)row * DOUT + lane];
    float m = v;
    #pragma unroll
    for (int off = 32; off >= 1; off >>= 1) m = fmaxf(m, __shfl_xor(m, off));
    float e = (lane < DOUT) ? __expf(v - m) : 0.f;
    float s = e;
    #pragma unroll
    for (int off = 32; off >= 1; off >>= 1) s += __shfl_xor(s, off);
    float lse = m + __logf(s);
    if (lane < DOUT)
        lsm[(size_t)row * DOUT + lane] = v - lse;
}

extern "C" void kernel_launch(void* const* d_in, const int* in_sizes, int n_in,
                              void* d_out, int out_size, void* d_ws, size_t ws_size,
                              hipStream_t stream) {
    const float* x  = (const float*)d_in[0];
    const int*   ei = (const int*)d_in[1];
    const float* W1 = (const float*)d_in[2];
    const float* b1 = (const float*)d_in[3];
    const float* W2 = (const float*)d_in[4];
    const float* b2 = (const float*)d_in[5];

    const int N = in_sizes[0] / DIN;
    const int E = in_sizes[1] / 2;
    const int* srcp = ei;
    const int* dstp = ei + E;
    const int SB = (N + 255) / 256;

    float* hs1  = (float*)d_ws;                   // N*96
    float* h1   = hs1 + (size_t)N * DH;           // N*96
    float* hs2  = h1  + (size_t)N * DH;           // N*40
    float* dinv = hs2 + (size_t)N * DOUT;         // N
    ushort* W1T = (ushort*)(dinv + N);            // 96*512 bf16
    int* cnt     = (int*)(W1T + (size_t)DH * DIN);// N
    int* cursor  = cnt + N;                       // N
    int* row_ptr = cursor + N;                    // N+1
    int* adj     = row_ptr + N + 1;               // E
    int* bsum    = adj + E;                       // SB
    int* boff    = bsum + SB;                     // SB

    float* out = (float*)d_out;                   // logits [N*40]
    float* lsm = out + (size_t)N * DOUT;          // log_softmax [N*40]

    const int gE = (E + 255) / 256;

    k_zero<<<SB, 256, 0, stream>>>(cnt, N);
    k_w1t<<<(DH * DIN) / 256, 256, 0, stream>>>(W1, W1T);
    k_hist<<<gE, 256, 0, stream>>>(dstp, cnt, E);
    k_blocksum<<<SB, 256, 0, stream>>>(cnt, bsum, N);
    k_scan_small<<<1, 256, 0, stream>>>(bsum, boff, SB);
    k_rowptr<<<SB, 256, 0, stream>>>(cnt, boff, row_ptr, cursor, dinv, N);
    k_fill<<<gE, 256, 0, stream>>>(srcp, dstp, cursor, adj, E);

    k_gemm1<<<(N + 127) / 128, 256, 0, stream>>>(x, W1T, dinv, hs1, N);
    k_agg1<<<(int)(((size_t)N * 24 + 255) / 256), 256, 0, stream>>>(row_ptr, adj, dinv, hs1, b1, h1, N);

    k_gemm2<<<(N + BM2 - 1) / BM2, 256, 0, stream>>>(h1, W2, dinv, hs2, N);
    k_agg2<<<(int)(((size_t)N * 10 + 255) / 256), 256, 0, stream>>>(row_ptr, adj, dinv, hs2, b2, out, N);

    k_softmax<<<(int)(((size_t)N * 64 + 255) / 256), 256, 0, stream>>>(out, lsm, N);
}

// Round 5
// 225.321 us; speedup vs baseline: 1.0673x; 1.0673x over previous
//
#include <hip/hip_runtime.h>
#include <cstdint>
#include <cstddef>

#define DIN 512
#define DH  96
#define DOUT 40

typedef __attribute__((ext_vector_type(8))) short s8v;
typedef __attribute__((ext_vector_type(4))) float f4v;

__device__ __forceinline__ ushort f2bf(float f) {
    uint u = __float_as_uint(f);
    u += 0x7fffu + ((u >> 16) & 1u);   // RNE
    return (ushort)(u >> 16);
}
__device__ __forceinline__ float bflo(uint u) { return __uint_as_float(u << 16); }
__device__ __forceinline__ float bfhi(uint u) { return __uint_as_float(u & 0xffff0000u); }

// ---------- prep: zero cnt + W1T bf16 [96][512] + W2T bf16 [48][96] (zero-padded) ----------
__global__ __launch_bounds__(256) void k_prep(
    const float* __restrict__ W1, const float* __restrict__ W2,
    int* __restrict__ cnt, ushort* __restrict__ W1T, ushort* __restrict__ W2T, int N)
{
    int i = blockIdx.x * 256 + threadIdx.x;
    if (i < N) cnt[i] = 0;
    if (i < DIN * DH) {                       // 49152
        int k = i / DH, n = i % DH;
        W1T[(size_t)n * DIN + k] = f2bf(W1[i]);
    }
    if (i < 48 * DH) {                        // 4608
        int n = i / DH, k = i % DH;
        W2T[i] = (n < DOUT) ? f2bf(W2[(size_t)k * DOUT + n]) : (ushort)0;
    }
}

// ---------- CSR build ----------
__global__ __launch_bounds__(256) void k_hist(const int* __restrict__ dst, int* __restrict__ cnt, int E) {
    int e = blockIdx.x * 256 + threadIdx.x;
    if (e < E) atomicAdd(&cnt[dst[e]], 1);
}

__global__ __launch_bounds__(256) void k_blocksum(const int* __restrict__ cnt, int* __restrict__ bsum, int N) {
    int i = blockIdx.x * 256 + threadIdx.x;
    int c = (i < N) ? cnt[i] : 0;
    #pragma unroll
    for (int off = 32; off >= 1; off >>= 1) c += __shfl_down(c, off, 64);
    __shared__ int wsum[4];
    if ((threadIdx.x & 63) == 0) wsum[threadIdx.x >> 6] = c;
    __syncthreads();
    if (threadIdx.x == 0) bsum[blockIdx.x] = wsum[0] + wsum[1] + wsum[2] + wsum[3];
}

__global__ __launch_bounds__(256) void k_scan_small(const int* __restrict__ bsum, int* __restrict__ boff, int SB) {
    __shared__ int p[256];
    int tid = threadIdx.x;
    int v = (tid < SB) ? bsum[tid] : 0;
    p[tid] = v;
    __syncthreads();
    #pragma unroll
    for (int off = 1; off < 256; off <<= 1) {
        int t = (tid >= off) ? p[tid - off] : 0;
        __syncthreads();
        p[tid] += t;
        __syncthreads();
    }
    if (tid < SB) boff[tid] = p[tid] - v;   // exclusive
}

__global__ __launch_bounds__(256) void k_rowptr(
    const int* __restrict__ cnt, const int* __restrict__ boff,
    int* __restrict__ row_ptr, int* __restrict__ cursor,
    float* __restrict__ dinv, int N)
{
    __shared__ int p[256];
    int tid = threadIdx.x;
    int i = blockIdx.x * 256 + tid;
    int c = (i < N) ? cnt[i] : 0;
    p[tid] = c;
    __syncthreads();
    #pragma unroll
    for (int off = 1; off < 256; off <<= 1) {
        int t = (tid >= off) ? p[tid - off] : 0;
        __syncthreads();
        p[tid] += t;
        __syncthreads();
    }
    int excl = p[tid] - c;
    if (i < N) {
        int base = boff[blockIdx.x] + excl;
        row_ptr[i] = base;
        cursor[i]  = base;
        dinv[i] = rsqrtf(1.0f + (float)c);
        if (i == N - 1) row_ptr[N] = base + c;
    }
}

__global__ __launch_bounds__(256) void k_fill(
    const int* __restrict__ src, const int* __restrict__ dst,
    int* __restrict__ cursor, int* __restrict__ adj, int E)
{
    int e = blockIdx.x * 256 + threadIdx.x;
    if (e >= E) return;
    int pos = atomicAdd(&cursor[dst[e]], 1);
    adj[pos] = src[e];
}

// ---------- GEMM1 (MFMA bf16): hs1 = bf16((x @ W1) * dinv) ----------
#define G1_ASZ 8192   // 128*64 halfwords
#define G1_BSZ 6144   // 96*64 halfwords
__global__ __launch_bounds__(256) void k_gemm1(
    const float* __restrict__ x, const ushort* __restrict__ W1T,
    const float* __restrict__ dinv, ushort* __restrict__ hs1, int N)
{
    __shared__ ushort lds[2 * G1_ASZ + 2 * G1_BSZ];   // 56 KiB
    const int tid = threadIdx.x;
    const int row0 = blockIdx.x * 128;
    const int lane = tid & 63;
    const int w = tid >> 6;
    const int rb = (w >> 1) * 64;
    const int cb = (w & 1) * 48;
    const int lm = lane & 15;
    const int lq = lane >> 4;

    int aof[4][2], bof[3][2];
    #pragma unroll
    for (int i = 0; i < 4; ++i)
        #pragma unroll
        for (int ks = 0; ks < 2; ++ks) {
            int r = rb + i * 16 + lm;
            int c = ks * 32 + lq * 8;
            aof[i][ks] = r * 64 + (c ^ ((r & 7) << 3));
        }
    #pragma unroll
    for (int j = 0; j < 3; ++j)
        #pragma unroll
        for (int ks = 0; ks < 2; ++ks) {
            int n = cb + j * 16 + lm;
            int c = ks * 32 + lq * 8;
            bof[j][ks] = 2 * G1_ASZ + n * 64 + (c ^ ((n & 7) << 3));
        }

    f4v acc[4][3];
    #pragma unroll
    for (int i = 0; i < 4; ++i)
        #pragma unroll
        for (int j = 0; j < 3; ++j) acc[i][j] = (f4v)0.f;

    const int sr = tid >> 1;
    const int scb = (tid & 1) * 32;

    auto stage = [&](int kt, int buf) {
        int k0 = kt * 64;
        int gr = row0 + sr;
        ushort* A = lds + buf * G1_ASZ;
        #pragma unroll
        for (int s = 0; s < 4; ++s) {
            int c = scb + s * 8;
            float4 v0 = make_float4(0.f, 0.f, 0.f, 0.f), v1 = v0;
            if (gr < N) {
                const float* p = &x[(size_t)gr * DIN + k0 + c];
                v0 = *(const float4*)p;
                v1 = *(const float4*)(p + 4);
            }
            uint4 wv;
            wv.x = (uint)f2bf(v0.x) | ((uint)f2bf(v0.y) << 16);
            wv.y = (uint)f2bf(v0.z) | ((uint)f2bf(v0.w) << 16);
            wv.z = (uint)f2bf(v1.x) | ((uint)f2bf(v1.y) << 16);
            wv.w = (uint)f2bf(v1.z) | ((uint)f2bf(v1.w) << 16);
            *(uint4*)&A[sr * 64 + (c ^ ((sr & 7) << 3))] = wv;
        }
        ushort* B = lds + 2 * G1_ASZ + buf * G1_BSZ;
        #pragma unroll
        for (int it = 0; it < 3; ++it) {
            int ss = tid + it * 256;
            int n = ss >> 3, c = (ss & 7) * 8;
            uint4 wv = *(const uint4*)&W1T[(size_t)n * DIN + k0 + c];
            *(uint4*)&B[n * 64 + (c ^ ((n & 7) << 3))] = wv;
        }
    };

    stage(0, 0);
    for (int kt = 0; kt < 8; ++kt) {
        __syncthreads();
        if (kt < 7) stage(kt + 1, (kt + 1) & 1);
        const int ab = (kt & 1) * G1_ASZ;
        const int bb = (kt & 1) * G1_BSZ;
        #pragma unroll
        for (int ks = 0; ks < 2; ++ks) {
            s8v b0 = *(s8v*)&lds[bof[0][ks] + bb];
            s8v b1 = *(s8v*)&lds[bof[1][ks] + bb];
            s8v b2 = *(s8v*)&lds[bof[2][ks] + bb];
            #pragma unroll
            for (int i = 0; i < 4; ++i) {
                s8v a = *(s8v*)&lds[aof[i][ks] + ab];
                acc[i][0] = __builtin_amdgcn_mfma_f32_16x16x32_bf16(a, b0, acc[i][0], 0, 0, 0);
                acc[i][1] = __builtin_amdgcn_mfma_f32_16x16x32_bf16(a, b1, acc[i][1], 0, 0, 0);
                acc[i][2] = __builtin_amdgcn_mfma_f32_16x16x32_bf16(a, b2, acc[i][2], 0, 0, 0);
            }
        }
    }

    #pragma unroll
    for (int i = 0; i < 4; ++i) {
        int gr0 = row0 + rb + i * 16 + lq * 4;
        #pragma unroll
        for (int q = 0; q < 4; ++q) {
            int gr = gr0 + q;
            if (gr < N) {
                float di = dinv[gr];
                #pragma unroll
                for (int j = 0; j < 3; ++j)
                    hs1[(size_t)gr * DH + cb + j * 16 + lm] = f2bf(acc[i][j][q] * di);
            }
        }
    }
}

// ---------- agg1: wave per node; h1 = bf16(relu(dinv*(hs1_self + sum hs1[src]) + b1)) ----------
__global__ __launch_bounds__(256) void k_agg1(
    const int* __restrict__ row_ptr, const int* __restrict__ adj,
    const float* __restrict__ dinv, const ushort* __restrict__ hs1,
    const float* __restrict__ b1, ushort* __restrict__ h1, int N)
{
    int t = blockIdx.x * 256 + threadIdx.x;
    int node = t >> 6, lane = t & 63;
    if (node >= N) return;
    int c = lane << 1;                    // cols c, c+1
    const bool act = (c < DH);            // lanes 0..47 active

    float a0 = 0.f, a1 = 0.f;
    if (act) {
        uint u = *(const uint*)&hs1[(size_t)node * DH + c];   // self-loop
        a0 = bflo(u); a1 = bfhi(u);
    }
    int e = row_ptr[node], e1 = row_ptr[node + 1];
    for (; e + 3 < e1; e += 4) {
        int s0 = adj[e], s1 = adj[e + 1], s2 = adj[e + 2], s3 = adj[e + 3];
        if (act) {
            uint u0 = *(const uint*)&hs1[(size_t)s0 * DH + c];
            uint u1 = *(const uint*)&hs1[(size_t)s1 * DH + c];
            uint u2 = *(const uint*)&hs1[(size_t)s2 * DH + c];
            uint u3 = *(const uint*)&hs1[(size_t)s3 * DH + c];
            a0 += bflo(u0); a1 += bfhi(u0);
            a0 += bflo(u1); a1 += bfhi(u1);
            a0 += bflo(u2); a1 += bfhi(u2);
            a0 += bflo(u3); a1 += bfhi(u3);
        }
    }
    for (; e < e1; ++e) {
        int s = adj[e];
        if (act) {
            uint u = *(const uint*)&hs1[(size_t)s * DH + c];
            a0 += bflo(u); a1 += bfhi(u);
        }
    }
    if (act) {
        float di = dinv[node];
        float r0 = fmaxf(fmaf(a0, di, b1[c]), 0.f);
        float r1 = fmaxf(fmaf(a1, di, b1[c + 1]), 0.f);
        uint wv = (uint)f2bf(r0) | ((uint)f2bf(r1) << 16);
        *(uint*)&h1[(size_t)node * DH + c] = wv;
    }
}

// ---------- GEMM2 (MFMA bf16): hs2 = (h1 @ W2) * dinv, f32 out ----------
#define G2_HS 16384   // 128 rows * 128 stride halfwords
__global__ __launch_bounds__(256) void k_gemm2(
    const ushort* __restrict__ h1, const ushort* __restrict__ W2T,
    const float* __restrict__ dinv, float* __restrict__ hs2, int N)
{
    __shared__ ushort lds[G2_HS + 48 * 128];   // 32KB + 12KB
    const int tid = threadIdx.x;
    const int row0 = blockIdx.x * 128;

    // stage W2T: 48 x 96 = 576 uint4
    for (int f = tid; f < 576; f += 256) {
        int r = f / 12, c = (f % 12) * 8;
        uint4 v = *(const uint4*)&W2T[r * DH + c];
        *(uint4*)&lds[G2_HS + r * 128 + (c ^ ((r & 7) << 3))] = v;
    }
    // stage H: 128 rows x 96 halfwords; thread = (row, half)
    {
        int r = tid >> 1, half = tid & 1;
        int gr = row0 + r;
        #pragma unroll
        for (int i = 0; i < 6; ++i) {
            int c = half * 48 + i * 8;
            uint4 v = make_uint4(0, 0, 0, 0);
            if (gr < N) v = *(const uint4*)&h1[(size_t)gr * DH + c];
            *(uint4*)&lds[r * 128 + (c ^ ((r & 7) << 3))] = v;
        }
    }
    __syncthreads();

    const int lane = tid & 63, w = tid >> 6;
    const int rb = w * 32, lm = lane & 15, lq = lane >> 4;
    f4v acc[2][3];
    #pragma unroll
    for (int i = 0; i < 2; ++i)
        #pragma unroll
        for (int j = 0; j < 3; ++j) acc[i][j] = (f4v)0.f;

    #pragma unroll
    for (int ks = 0; ks < 3; ++ks) {
        int kk = ks * 32 + lq * 8;
        s8v b[3];
        #pragma unroll
        for (int j = 0; j < 3; ++j) {
            int n = j * 16 + lm;
            b[j] = *(s8v*)&lds[G2_HS + n * 128 + (kk ^ ((n & 7) << 3))];
        }
        #pragma unroll
        for (int i = 0; i < 2; ++i) {
            int r = rb + i * 16 + lm;
            s8v a = *(s8v*)&lds[r * 128 + (kk ^ ((r & 7) << 3))];
            #pragma unroll
            for (int j = 0; j < 3; ++j)
                acc[i][j] = __builtin_amdgcn_mfma_f32_16x16x32_bf16(a, b[j], acc[i][j], 0, 0, 0);
        }
    }

    #pragma unroll
    for (int i = 0; i < 2; ++i) {
        int gr0 = row0 + rb + i * 16 + lq * 4;
        #pragma unroll
        for (int q = 0; q < 4; ++q) {
            int gr = gr0 + q;
            if (gr < N) {
                float di = dinv[gr];
                #pragma unroll
                for (int j = 0; j < 3; ++j) {
                    int col = j * 16 + lm;
                    if (col < DOUT)
                        hs2[(size_t)gr * DOUT + col] = acc[i][j][q] * di;
                }
            }
        }
    }
}

// ---------- agg2 + bias + log_softmax fused: wave per node ----------
__global__ __launch_bounds__(256) void k_agg2sm(
    const int* __restrict__ row_ptr, const int* __restrict__ adj,
    const float* __restrict__ dinv, const float* __restrict__ hs2,
    const float* __restrict__ b2, float* __restrict__ out,
    float* __restrict__ lsm, int N)
{
    int t = blockIdx.x * 256 + threadIdx.x;
    int node = t >> 6, lane = t & 63;
    if (node >= N) return;
    const bool act = lane < DOUT;

    float acc = act ? hs2[(size_t)node * DOUT + lane] : 0.f;   // self-loop
    int e = row_ptr[node], e1 = row_ptr[node + 1];
    for (; e + 3 < e1; e += 4) {
        int s0 = adj[e], s1 = adj[e + 1], s2 = adj[e + 2], s3 = adj[e + 3];
        if (act) {
            float v0 = hs2[(size_t)s0 * DOUT + lane];
            float v1 = hs2[(size_t)s1 * DOUT + lane];
            float v2 = hs2[(size_t)s2 * DOUT + lane];
            float v3 = hs2[(size_t)s3 * DOUT + lane];
            acc += v0 + v1 + v2 + v3;
        }
    }
    for (; e < e1; ++e) {
        int s = adj[e];
        if (act) acc += hs2[(size_t)s * DOUT + lane];
    }

    float v = act ? fmaf(acc, dinv[node], b2[lane]) : -1e30f;
    float m = v;
    #pragma unroll
    for (int off = 32; off >= 1; off >>= 1) m = fmaxf(m, __shfl_xor(m, off));
    float ex = act ? __expf(v - m) : 0.f;
    float s = ex;
    #pragma unroll
    for (int off = 32; off >= 1; off >>= 1) s += __shfl_xor(s, off);
    float lse = m + __logf(s);
    if (act) {
        out[(size_t)node * DOUT + lane] = v;
        lsm[(size_t)node * DOUT + lane] = v - lse;
    }
}

extern "C" void kernel_launch(void* const* d_in, const int* in_sizes, int n_in,
                              void* d_out, int out_size, void* d_ws, size_t ws_size,
                              hipStream_t stream) {
    const float* x  = (const float*)d_in[0];
    const int*   ei = (const int*)d_in[1];
    const float* W1 = (const float*)d_in[2];
    const float* b1 = (const float*)d_in[3];
    const float* W2 = (const float*)d_in[4];
    const float* b2 = (const float*)d_in[5];

    const int N = in_sizes[0] / DIN;
    const int E = in_sizes[1] / 2;
    const int* srcp = ei;
    const int* dstp = ei + E;
    const int SB = (N + 255) / 256;

    ushort* hs1 = (ushort*)d_ws;                    // N*96 bf16
    ushort* h1  = hs1 + (size_t)N * DH;             // N*96 bf16
    float* hs2  = (float*)(h1 + (size_t)N * DH);    // N*40 f32
    float* dinv = hs2 + (size_t)N * DOUT;           // N
    ushort* W1T = (ushort*)(dinv + N);              // 96*512 bf16
    ushort* W2T = W1T + (size_t)DH * DIN;           // 48*96 bf16
    int* cnt     = (int*)(W2T + 48 * DH);           // N
    int* cursor  = cnt + N;                         // N
    int* row_ptr = cursor + N;                      // N+1
    int* adj     = row_ptr + N + 1;                 // E
    int* bsum    = adj + E;                         // SB
    int* boff    = bsum + SB;                       // SB

    float* out = (float*)d_out;                     // logits [N*40]
    float* lsm = out + (size_t)N * DOUT;            // log_softmax [N*40]

    const int gE = (E + 255) / 256;

    k_prep<<<SB, 256, 0, stream>>>(W1, W2, cnt, W1T, W2T, N);
    k_hist<<<gE, 256, 0, stream>>>(dstp, cnt, E);
    k_blocksum<<<SB, 256, 0, stream>>>(cnt, bsum, N);
    k_scan_small<<<1, 256, 0, stream>>>(bsum, boff, SB);
    k_rowptr<<<SB, 256, 0, stream>>>(cnt, boff, row_ptr, cursor, dinv, N);
    k_fill<<<gE, 256, 0, stream>>>(srcp, dstp, cursor, adj, E);

    k_gemm1<<<(N + 127) / 128, 256, 0, stream>>>(x, W1T, dinv, hs1, N);
    k_agg1<<<(int)(((size_t)N * 64 + 255) / 256), 256, 0, stream>>>(row_ptr, adj, dinv, hs1, b1, h1, N);

    k_gemm2<<<(N + 127) / 128, 256, 0, stream>>>(h1, W2T, dinv, hs2, N);
    k_agg2sm<<<(int)(((size_t)N * 64 + 255) / 256), 256, 0, stream>>>(row_ptr, adj, dinv, hs2, b2, out, lsm, N);
}